// Round 10
// baseline (257.073 us; speedup 1.0000x reference)
//
#include <hip/hip_runtime.h>
#include <math.h>

#define C_IN 72
#define RST 97               // row-buffer stride (floats)
#define NFRAG 21             // 7 n-tiles x 3 k-chunks
#define STG_T (16 * C_IN)    // ushorts per tensor stage tile: [16 pos][72 ch]
#define WF_BYTES (NFRAG * 64 * 16)   // 21504 B: B-fragments staged in LDS
#define WAVE_LDS 6912        // per-wave union(stage 6912 B, rowbuf 6208 B)

typedef short short8  __attribute__((ext_vector_type(8)));
typedef float floatx4 __attribute__((ext_vector_type(4)));

// volatile asm load: compiler cannot sink/split/reorder -> true batch.
#define GLD4(dst, ptr) \
    asm volatile("global_load_dwordx4 %0, %1, off" : "=v"(dst) : "v"(ptr))

__device__ __forceinline__ unsigned short f2bf(float f) {   // RNE float->bf16
    unsigned u = __float_as_uint(f);
    u += 0x7FFFu + ((u >> 16) & 1u);
    return (unsigned short)(u >> 16);
}
__device__ __forceinline__ float sigf(float x) {
    return __builtin_amdgcn_rcpf(1.0f + __expf(-x));
}

// ---- kernel 1: pre-pack all B fragments (bf16, MFMA B-operand layout) ----
__global__ void __launch_bounds__(256)
build_bfrags_kernel(const float* __restrict__ w_reg,
                    const float* __restrict__ w_obj,
                    const float* __restrict__ w_cls,
                    short8* __restrict__ frags)
{
    int idx = blockIdx.x * 256 + threadIdx.x;
    if (idx >= NFRAG * 64) return;
    int lane = idx & 63;
    int fi   = idx >> 6;
    int tile = fi / 3, kc = fi - tile * 3;
    int m = lane & 15, quad = lane >> 4;
    const float* wrow;
    bool valid = true;
    if (tile == 0)      { wrow = w_reg + m * C_IN; valid = (m < 12); }
    else if (tile == 1) { wrow = w_obj + m * C_IN; valid = (m < 3); }
    else                { wrow = w_cls + ((tile - 2) * 16 + m) * C_IN; }
    short8 r = {0, 0, 0, 0, 0, 0, 0, 0};
    if (valid && !(kc == 2 && quad != 0)) {
        const float* p = wrow + kc * 32 + quad * 8;
#pragma unroll
        for (int j = 0; j < 8; ++j) r[j] = (short)f2bf(p[j]);
    }
    frags[fi * 64 + lane] = r;
}

// ---- kernel 2: R9/R10 request-count restructure.
// Theory: all 77-80us variants shared one invariant -- ~6.6M 64B L2 requests
// (features 1.9M + wfrag-from-L2 2.7M + stores 2.0M); batching/swizzle/bytes
// changes were all neutral => request-rate cap. This version cuts requests 37%:
//   * wfrag staged to LDS ONCE per block (2.7M -> 0.17M), MFMA B = ds_read_b128
//   * 4 slabs per wave (64 consecutive positions), 500 blocks x 4 waves,
//     single dispatch round (500 <= resident capacity), no tail
//   * 1-deep pipeline: slab i+1's 15 volatile loads fly during slab i's
//     MFMA/decode/write; counted vmcnt(16) so prev stores never serialize
//   * writer uses dwordx4 stores (16/slab) -> exact vmcnt bookkeeping ----
__global__ void __launch_bounds__(256)
yolo_head_kernel(const float* __restrict__ fr0, const float* __restrict__ fo0, const float* __restrict__ fc0,
                 const float* __restrict__ fr1, const float* __restrict__ fo1, const float* __restrict__ fc1,
                 const float* __restrict__ b_reg, const float* __restrict__ b_obj,
                 const float* __restrict__ b_cls,
                 const short8* __restrict__ wfrag,
                 float* __restrict__ out)
{
    __shared__ __align__(16) unsigned char smem[WF_BYTES + 4 * WAVE_LDS];  // 49152 B
    short8* const wfl = (short8*)smem;
    const int tid  = threadIdx.x;
    const int wid  = tid >> 6;
    const int lane = tid & 63;
    unsigned short* const stage = (unsigned short*)(smem + WF_BYTES + wid * WAVE_LDS);
    float*          const row   = (float*)         (smem + WF_BYTES + wid * WAVE_LDS);

    // ---- cooperative wfrag stage: 21.5 KB once per block ----
    for (int j = tid; j < NFRAG * 64; j += 256) wfl[j] = wfrag[j];
    __syncthreads();     // compiler drains vmcnt/lgkmcnt before barrier

    const int m    = lane & 15;
    const int quad = lane >> 4;
    const int chg  = lane >> 2;    // channel-in-group 0..15
    const int pg   = lane & 3;     // position quarter 0..3

    // wave -> 4 consecutive slabs, same level. L0: waves 0..1599 (slabs 0..6399,
    // image boundary 100 % 4 == 0 so groups never straddle mid-group constants).
    const int wg = blockIdx.x * 4 + wid;        // 0..1999
    int lvl, HW, W, LO, sbase;
    const float *fr, *fo, *fc;
    if (wg < 1600) { lvl = 0; HW = 1600; W = 40; LO = 0;    sbase = wg * 4;
                     fr = fr0; fo = fo0; fc = fc0; }
    else           { lvl = 1; HW = 400;  W = 20; LO = 4800; sbase = (wg - 1600) * 4;
                     fr = fr1; fo = fo1; fc = fc1; }
    const float STRIDE = lvl ? 32.0f : 16.0f;
    const float* srcs[3] = {fr, fo, fc};

    // ---- wave-invariant decode constants ----
    const int a_ = m >> 2, k_ = m & 3;
    float anch;
    {
        float e0, e1;
        if (lvl == 0) { e0 = a_ == 0 ? 12.64f  : a_ == 1 ? 37.88f  : 55.71f;
                        e1 = a_ == 0 ? 19.39f  : a_ == 1 ? 51.48f  : 138.31f; }
        else          { e0 = a_ == 0 ? 126.91f : a_ == 1 ? 131.57f : 279.92f;
                        e1 = a_ == 0 ? 78.23f  : a_ == 1 ? 214.55f : 258.87f; }
        anch = (k_ == 3) ? e1 : e0;
    }
    const float brg = b_reg[m < 12 ? m : 0];
    const float bob = b_obj[m < 3 ? m : 0];
    float bcl[5];
#pragma unroll
    for (int nt = 0; nt < 5; ++nt) bcl[nt] = b_cls[nt * 16 + m];

    // ---- pipelined feature loads: 15 dwordx4 per slab, volatile-forced ----
    floatx4 ld[3][5];
    auto issueT1 = [&](int S) {
        int b, pos0;
        if (lvl == 0) { b = S / 100; pos0 = (S - b * 100) * 16; }
        else          { b = S / 25;  pos0 = (S - b * 25) * 16; }
        const int fb = b * C_IN * HW + pos0 + pg * 4;
#pragma unroll
        for (int t = 0; t < 3; ++t) {
            const float* sp = srcs[t] + fb;
#pragma unroll
            for (int g = 0; g < 4; ++g) {
                const float* p = sp + (g * 16 + chg) * HW;
                GLD4(ld[t][g], p);
            }
        }
        if (lane < 32) {
#pragma unroll
            for (int t = 0; t < 3; ++t) {
                const float* p = srcs[t] + fb + (64 + chg) * HW;
                GLD4(ld[t][4], p);
            }
        }
    };

    issueT1(sbase);

#pragma unroll
    for (int i = 0; i < 4; ++i) {
        const int S = sbase + i;
        int b, pos0;
        if (lvl == 0) { b = S / 100; pos0 = (S - b * 100) * 16; }
        else          { b = S / 25;  pos0 = (S - b * 25) * 16; }

        // wait this slab's 15 loads; prev slab's 16 stores (newer) may stay in flight
        if (i == 0) asm volatile("s_waitcnt vmcnt(0)" ::: "memory");
        else        asm volatile("s_waitcnt vmcnt(16)" ::: "memory");
        __builtin_amdgcn_sched_barrier(0);   // rule 18: cvts are register-only

        // ---- stage: cvt bf16 + transpose-scatter into stage[t][pos][ch] ----
#pragma unroll
        for (int t = 0; t < 3; ++t) {
#pragma unroll
            for (int g = 0; g < 4; ++g)
#pragma unroll
                for (int ii = 0; ii < 4; ++ii)
                    stage[t * STG_T + (pg * 4 + ii) * C_IN + g * 16 + chg] = f2bf(ld[t][g][ii]);
            if (lane < 32)
#pragma unroll
                for (int ii = 0; ii < 4; ++ii)
                    stage[t * STG_T + (pg * 4 + ii) * C_IN + 64 + chg] = f2bf(ld[t][4][ii]);
        }
        asm volatile("s_waitcnt lgkmcnt(0)" ::: "memory");

        // ---- A fragments: direct b128 reads (exact MFMA layout) ----
        short8 af[3][3];
#pragma unroll
        for (int t = 0; t < 3; ++t) {
            const unsigned short* tp = stage + t * STG_T + m * C_IN;
            af[t][0] = *(const short8*)(tp + quad * 8);
            af[t][1] = *(const short8*)(tp + 32 + quad * 8);
            short8 v = *(const short8*)(tp + 64);
            if (quad) v = (short8){0, 0, 0, 0, 0, 0, 0, 0};
            af[t][2] = v;
        }
        asm volatile("s_waitcnt lgkmcnt(0)" ::: "memory");  // frags landed; region reusable

        // ---- pipeline: next slab's loads fly under MFMA/decode/writer ----
        if (i < 3) issueT1(S + 1);

        // ---- MFMA: 21 tiles, B streamed from LDS (ds_read_b128) ----
        floatx4 accR = {0, 0, 0, 0}, accO = {0, 0, 0, 0}, accC[5];
#pragma unroll
        for (int kc = 0; kc < 3; ++kc)
            accR = __builtin_amdgcn_mfma_f32_16x16x32_bf16(af[0][kc], wfl[(0 * 3 + kc) * 64 + lane], accR, 0, 0, 0);
#pragma unroll
        for (int kc = 0; kc < 3; ++kc)
            accO = __builtin_amdgcn_mfma_f32_16x16x32_bf16(af[1][kc], wfl[(1 * 3 + kc) * 64 + lane], accO, 0, 0, 0);
#pragma unroll
        for (int nt = 0; nt < 5; ++nt) {
            floatx4 a4 = {0, 0, 0, 0};
#pragma unroll
            for (int kc = 0; kc < 3; ++kc)
                a4 = __builtin_amdgcn_mfma_f32_16x16x32_bf16(af[2][kc], wfl[((nt + 2) * 3 + kc) * 64 + lane], a4, 0, 0, 0);
            accC[nt] = a4;
        }

        // ---- decode into rowbuf (unions with stage; frags already consumed) ----
#pragma unroll
        for (int ii = 0; ii < 4; ++ii) {
            const int prel = quad * 4 + ii;
            const int pg_  = pos0 + prel;
            const int gyi  = lvl ? (pg_ / 20) : (pg_ / 40);
            const float gx = (float)(pg_ - gyi * W);
            const float gy = (float)gyi;

            if (m < 12) {
                float sg = sigf(accR[ii] + brg);
                float v;
                if (k_ == 0)      v = (sg * 2.0f - 0.5f + gx) * STRIDE;
                else if (k_ == 1) v = (sg * 2.0f - 0.5f + gy) * STRIDE;
                else { float t2 = sg * 2.0f; v = t2 * t2 * anch; }
                row[prel * RST + a_ * 5 + k_] = v;
            }
            if (m < 3)
                row[prel * RST + m * 5 + 4] = sigf(accO[ii] + bob);

            float e[5];
            float s = 0.f;
#pragma unroll
            for (int nt = 0; nt < 5; ++nt) {
                e[nt] = __expf(accC[nt][ii] + bcl[nt]);
                s += e[nt];
            }
            s += __shfl_xor(s, 1, 16);
            s += __shfl_xor(s, 2, 16);
            s += __shfl_xor(s, 4, 16);
            s += __shfl_xor(s, 8, 16);
            const float inv = __builtin_amdgcn_rcpf(s);
#pragma unroll
            for (int nt = 0; nt < 5; ++nt)
                row[prel * RST + 15 + nt * 16 + m] = e[nt] * inv;
        }
        asm volatile("s_waitcnt lgkmcnt(0)" ::: "memory");  // rowbuf visible to writer

        // ---- writer: 16 dwordx4 stores/slab (lane owns 4 consecutive floats
        // of the 4080-float slab; magic-div by 255 maps flat->row/slot) ----
        float* outp = out + ((size_t)b * 510000 + LO * 85 + pos0 * 255);
#pragma unroll
        for (int s = 0; s < 16; ++s) {
            if (!(s == 15 && lane >= 60)) {          // F 4080..4095 don't exist
                floatx4 v;
#pragma unroll
                for (int j = 0; j < 4; ++j) {
                    const int F  = s * 256 + lane * 4 + j;
                    const int p  = (F * 4113) >> 20;      // floor(F/255), F<4096
                    const int k  = F - p * 255;
                    const int a  = (k >= 85) + (k >= 170);
                    const int kk = k - a * 85;
                    const int wi = (kk < 5) ? (a * 5 + kk) : (15 + (kk - 5));
                    v[j] = row[p * RST + wi];
                }
                *(floatx4*)(outp + s * 256 + lane * 4) = v;
            }
        }
    }
}

extern "C" void kernel_launch(void* const* d_in, const int* in_sizes, int n_in,
                              void* d_out, int out_size, void* d_ws, size_t ws_size,
                              hipStream_t stream) {
    (void)in_sizes; (void)n_in; (void)ws_size; (void)out_size;
    const float* fr0  = (const float*)d_in[0];
    const float* fo0  = (const float*)d_in[1];
    const float* fc0  = (const float*)d_in[2];
    const float* fr1  = (const float*)d_in[3];
    const float* fo1  = (const float*)d_in[4];
    const float* fc1  = (const float*)d_in[5];
    const float* wreg = (const float*)d_in[6];
    const float* breg = (const float*)d_in[7];
    const float* wobj = (const float*)d_in[8];
    const float* bobj = (const float*)d_in[9];
    const float* wcls = (const float*)d_in[10];
    const float* bcls = (const float*)d_in[11];
    float* out = (float*)d_out;
    short8* frags = (short8*)d_ws;    // 21*64*16 = 21504 B

    // d_ws is re-poisoned before every call -> rebuild fragments every call
    build_bfrags_kernel<<<6, 256, 0, stream>>>(wreg, wobj, wcls, frags);

    // 500 blocks x 4 waves x 4 slabs = 8000 slabs; single resident round
    yolo_head_kernel<<<500, 256, 0, stream>>>(
        fr0, fo0, fc0, fr1, fo1, fc1,
        breg, bobj, bcls, frags, out);
}